// Round 5
// baseline (241.902 us; speedup 1.0000x reference)
//
#include <hip/hip_runtime.h>
#include <float.h>
#include <math.h>

#define NV 50257
#define D 128
#define B 2048
#define C 10

#define NVPAD 50272                 // 3142 * 16
#define NTILES (NVPAD / 16)         // 3142 col-tiles of 16
#define NSTREAM 256                 // vocab streams (k_final depends on this)
#define NG4 (NVPAD * D / 4)         // float4 count of padded W_gen
#define LOG2E 1.44269504088896f

typedef __attribute__((ext_vector_type(8))) short short8;
typedef __attribute__((ext_vector_type(4))) float float4v;

__device__ __forceinline__ float softplus_f(float x) {
    return fmaxf(x, 0.f) + log1pf(expf(-fabsf(x)));
}

__device__ __forceinline__ short f2bf(float f) {
    unsigned u = __float_as_uint(f);
    unsigned r = (u + 0x7FFFu + ((u >> 16) & 1u)) >> 16;   // RNE
    return (short)r;
}

// ---------------- Kernel W: bf16 converts + bg2 table + out zeroing ----------------
__global__ __launch_bounds__(256) void k_convert(
    const float* __restrict__ wg, const float* __restrict__ waff,
    const float* __restrict__ wmu, const float* __restrict__ wsig,
    const float* __restrict__ b_gen,
    short* __restrict__ wg_o, short* __restrict__ waff_o,
    short* __restrict__ wmu_o, short* __restrict__ wsig_o,
    float* __restrict__ bg2, float* __restrict__ out)
{
    const int i4 = blockIdx.x * 256 + threadIdx.x;      // float4 index
    if (i4 == 0) out[0] = 0.f;
    if (i4 < NG4) {
        const int e0 = i4 * 4;
        short4 o;
        if (e0 < NV * D) {
            const float4 g = ((const float4*)wg)[i4];
            o.x = f2bf(g.x); o.y = f2bf(g.y); o.z = f2bf(g.z); o.w = f2bf(g.w);
        } else {
            o.x = o.y = o.z = o.w = 0;
        }
        ((short4*)wg_o)[i4] = o;
        return;
    }
    const int j = i4 - NG4;
    if (j < 16384) {
        const float4* src; short4* dst; int jj;
        if (j < 8192)       { src = (const float4*)waff; dst = (short4*)waff_o; jj = j; }
        else if (j < 12288) { src = (const float4*)wmu;  dst = (short4*)wmu_o;  jj = j - 8192; }
        else                { src = (const float4*)wsig; dst = (short4*)wsig_o; jj = j - 12288; }
        const float4 g = src[jj];
        short4 o;
        o.x = f2bf(g.x); o.y = f2bf(g.y); o.z = f2bf(g.z); o.w = f2bf(g.w);
        dst[jj] = o;
    } else {
        const int jj = j - 16384;                       // bg2 float4 index
        if (jj < NVPAD / 4) {
            const int e0 = jj * 4;
            float4 o;
            o.x = (e0 + 0 < NV) ? b_gen[e0 + 0] * LOG2E : -INFINITY;
            o.y = (e0 + 1 < NV) ? b_gen[e0 + 1] * LOG2E : -INFINITY;
            o.z = (e0 + 2 < NV) ? b_gen[e0 + 2] * LOG2E : -INFINITY;
            o.w = (e0 + 3 < NV) ? b_gen[e0 + 3] * LOG2E : -INFINITY;
            ((float4*)bg2)[jj] = o;
        }
    }
}

// ---------------- Kernel A1: GEMM1 partial (context halves across blocks) ----------------
// grid (128, 2), block 256. Block (rt,h): U = center@W1^T (redundant), contexts
// c in [h*5, h*5+5) split over 4 waves; partial H summed in LDS, written fp32 to
// hpart[h][row][d] (linear layout = free C->A transpose for k_infer2).
__global__ __launch_bounds__(256) void k_infer1(
    const int* __restrict__ x_batch, const int* __restrict__ ctxw,
    const float* __restrict__ inf_emb,
    const short* __restrict__ waff_bf, const float* __restrict__ b_aff,
    float* __restrict__ hpart)
{
    const int b0 = blockIdx.x * 16;
    const int h = blockIdx.y;
    const int t = threadIdx.x;
    const int wv = t >> 6;
    const int lane = t & 63;
    const int col16 = lane & 15;
    const int quad = lane >> 4;

    __shared__ float hsp[4][16][132];

    const int brow = b0 + col16;
    const int cidx = x_batch[brow];

    // center A-frags
    short8 ce[4];
    #pragma unroll
    for (int ks = 0; ks < 4; ++ks) {
        const float* p = inf_emb + (size_t)cidx * D + ks * 32 + quad * 8;
        const float4 g0 = *(const float4*)p;
        const float4 g1 = *(const float4*)(p + 4);
        short8 v;
        v[0] = f2bf(g0.x); v[1] = f2bf(g0.y); v[2] = f2bf(g0.z); v[3] = f2bf(g0.w);
        v[4] = f2bf(g1.x); v[5] = f2bf(g1.y); v[6] = f2bf(g1.z); v[7] = f2bf(g1.w);
        ce[ks] = v;
    }

    // U = center @ W1^T
    float4v U[8];
    #pragma unroll
    for (int dt = 0; dt < 8; ++dt) {
        float4v acc = {0.f, 0.f, 0.f, 0.f};
        #pragma unroll
        for (int ks = 0; ks < 4; ++ks) {
            const short8 bw = *(const short8*)(waff_bf + (dt * 16 + col16) * 256 + ks * 32 + quad * 8);
            acc = __builtin_amdgcn_mfma_f32_16x16x32_bf16(ce[ks], bw, acc, 0, 0, 0);
        }
        U[dt] = acc;
    }
    float ba[8];
    #pragma unroll
    for (int dt = 0; dt < 8; ++dt) ba[dt] = b_aff[dt * 16 + col16];

    float4v H[8];
    #pragma unroll
    for (int dt = 0; dt < 8; ++dt) H[dt] = (float4v){0.f, 0.f, 0.f, 0.f};

    for (int c = h * 5 + wv; c < h * 5 + 5; c += 4) {
        const int widx = ctxw[brow * C + c];
        short8 cx[4];
        #pragma unroll
        for (int ks = 0; ks < 4; ++ks) {
            const float* p = inf_emb + (size_t)widx * D + ks * 32 + quad * 8;
            const float4 g0 = *(const float4*)p;
            const float4 g1 = *(const float4*)(p + 4);
            short8 v;
            v[0] = f2bf(g0.x); v[1] = f2bf(g0.y); v[2] = f2bf(g0.z); v[3] = f2bf(g0.w);
            v[4] = f2bf(g1.x); v[5] = f2bf(g1.y); v[6] = f2bf(g1.z); v[7] = f2bf(g1.w);
            cx[ks] = v;
        }
        #pragma unroll
        for (int dt = 0; dt < 8; ++dt) {
            float4v a = {0.f, 0.f, 0.f, 0.f};
            #pragma unroll
            for (int ks = 0; ks < 4; ++ks) {
                const short8 bw = *(const short8*)(waff_bf + (dt * 16 + col16) * 256 + 128 + ks * 32 + quad * 8);
                a = __builtin_amdgcn_mfma_f32_16x16x32_bf16(cx[ks], bw, a, 0, 0, 0);
            }
            #pragma unroll
            for (int r = 0; r < 4; ++r)
                H[dt][r] += fmaxf(U[dt][r] + a[r] + ba[dt], 0.f);
        }
    }

    // per-wave partial -> LDS (C-layout scatter), then sum 4 waves, write global
    #pragma unroll
    for (int dt = 0; dt < 8; ++dt)
        #pragma unroll
        for (int r = 0; r < 4; ++r)
            hsp[wv][quad * 4 + r][dt * 16 + col16] = H[dt][r];
    __syncthreads();

    #pragma unroll
    for (int i = t; i < 16 * 128; i += 256) {
        const int row = i >> 7, d = i & 127;
        const float s = hsp[0][row][d] + hsp[1][row][d] + hsp[2][row][d] + hsp[3][row][d];
        hpart[((size_t)h * B + b0 + row) * D + d] = s;
    }
}

// ---------------- Kernel A2: combine halves, GEMM2 (mu/sig), epilogue ----------------
// grid 128, block 256. ha read straight from global hpart (A-layout naturally).
__global__ __launch_bounds__(256) void k_infer2(
    const int* __restrict__ x_batch, const float* __restrict__ eps,
    const float* __restrict__ hpart,
    const short* __restrict__ wmu_bf, const float* __restrict__ b_mu,
    const short* __restrict__ wsig_bf, const float* __restrict__ b_sig,
    const float* __restrict__ gen_sig_emb,
    float* __restrict__ z_out, short* __restrict__ zb_out,
    float* __restrict__ kl_out)
{
    const int b0 = blockIdx.x * 16;
    const int t = threadIdx.x;
    const int wv = t >> 6;
    const int lane = t & 63;
    const int col16 = lane & 15;
    const int quad = lane >> 4;

    __shared__ float kl_s[4][16];

    // ha = hpart[0] + hpart[1], A-layout
    short8 ha[4];
    #pragma unroll
    for (int ks = 0; ks < 4; ++ks) {
        const int off = ks * 32 + quad * 8;
        const float* p0 = hpart + ((size_t)b0 + col16) * D + off;
        const float* p1 = p0 + (size_t)B * D;
        const float4 a0 = *(const float4*)p0;
        const float4 a1 = *(const float4*)(p0 + 4);
        const float4 b0v = *(const float4*)p1;
        const float4 b1v = *(const float4*)(p1 + 4);
        short8 v;
        v[0] = f2bf(a0.x + b0v.x); v[1] = f2bf(a0.y + b0v.y);
        v[2] = f2bf(a0.z + b0v.z); v[3] = f2bf(a0.w + b0v.w);
        v[4] = f2bf(a1.x + b1v.x); v[5] = f2bf(a1.y + b1v.y);
        v[6] = f2bf(a1.z + b1v.z); v[7] = f2bf(a1.w + b1v.w);
        ha[ks] = v;
    }

    int xb2[4];
    #pragma unroll
    for (int r = 0; r < 4; ++r) xb2[r] = x_batch[b0 + quad * 4 + r];

    float klp[4] = {0.f, 0.f, 0.f, 0.f};
    #pragma unroll
    for (int p = 0; p < 2; ++p) {
        const int nt = wv * 2 + p;
        float4v mu4 = {0.f, 0.f, 0.f, 0.f};
        float4v sg4 = {0.f, 0.f, 0.f, 0.f};
        #pragma unroll
        for (int ks = 0; ks < 4; ++ks) {
            const short8 bm = *(const short8*)(wmu_bf + (nt * 16 + col16) * 128 + ks * 32 + quad * 8);
            const short8 bs = *(const short8*)(wsig_bf + (nt * 16 + col16) * 128 + ks * 32 + quad * 8);
            mu4 = __builtin_amdgcn_mfma_f32_16x16x32_bf16(ha[ks], bm, mu4, 0, 0, 0);
            sg4 = __builtin_amdgcn_mfma_f32_16x16x32_bf16(ha[ks], bs, sg4, 0, 0, 0);
        }
        const int d = nt * 16 + col16;
        const float bmu = b_mu[d];
        const float bsg = b_sig[d];
        #pragma unroll
        for (int r = 0; r < 4; ++r) {
            const int b = b0 + quad * 4 + r;
            const float mu = mu4[r] + bmu;
            const float sg = sg4[r] + bsg;
            const float isig = softplus_f(sg);
            const float e = eps[b * D + d];
            const float zz = fmaf(e, isig, mu);
            z_out[b * D + d] = zz;
            zb_out[b * D + d] = f2bf(zz);
            const float gs = softplus_f(gen_sig_emb[(size_t)xb2[r] * D + d]);
            const float diff = mu - gs;
            klp[r] += logf(gs / isig) + (isig * isig + diff * diff) / (2.f * gs * gs) - 0.5f;
        }
    }
    #pragma unroll
    for (int off = 1; off < 16; off <<= 1)
        #pragma unroll
        for (int r = 0; r < 4; ++r)
            klp[r] += __shfl_xor(klp[r], off, 64);
    if (col16 == 0) {
        #pragma unroll
        for (int r = 0; r < 4; ++r)
            kl_s[wv][quad * 4 + r] = klp[r];
    }
    __syncthreads();
    if (t < 16) kl_out[b0 + t] = kl_s[0][t] + kl_s[1][t] + kl_s[2][t] + kl_s[3][t];
}

// ---------------- Kernel B: MFMA sum-exp; 2048 blocks -> 32 waves/CU ----------------
// bid = x*256 + g; g%8 = XCD; sid = (g&7)*32 + (g>>3): all 8 row-blocks of a
// stream land on one XCD; per-XCD L2 set = 32 streams (~1.6 MB).
__global__ __launch_bounds__(256) void k_lse_mfma(
    const short* __restrict__ zb, const short* __restrict__ wb,
    const float* __restrict__ bg2t, float* __restrict__ part_s)
{
    const int bid = blockIdx.x;
    const int g = bid & 255;
    const int sid = ((g & 7) << 5) | (g >> 3);     // 0..255
    const int x = bid >> 8;                         // row block 0..7 (256 rows each)
    const int t = threadIdx.x;
    const int wv = t >> 6;
    const int lane = t & 63;
    const int col16 = lane & 15;
    const int quad = lane >> 4;
    const int rowbase = x * 256 + wv * 64;

    short8 afrag[4][4];
    #pragma unroll
    for (int rt = 0; rt < 4; ++rt)
        #pragma unroll
        for (int ks = 0; ks < 4; ++ks)
            afrag[rt][ks] = *(const short8*)(zb + (rowbase + rt * 16 + col16) * D
                                                + ks * 32 + quad * 8);

    float sums[4][4];
    #pragma unroll
    for (int rt = 0; rt < 4; ++rt)
        #pragma unroll
        for (int r = 0; r < 4; ++r) sums[rt][r] = 0.f;

    for (int tile = sid; tile < NTILES; tile += NSTREAM) {
        const int col = tile * 16 + col16;
        const short* wp = wb + (size_t)col * D + quad * 8;
        short8 bfrag[4];
        #pragma unroll
        for (int ks = 0; ks < 4; ++ks)
            bfrag[ks] = *(const short8*)(wp + ks * 32);
        const float bg2 = bg2t[col];               // padded: -inf on pad cols

        #pragma unroll
        for (int rt = 0; rt < 4; ++rt) {
            float4v c = {0.f, 0.f, 0.f, 0.f};
            #pragma unroll
            for (int ks = 0; ks < 4; ++ks)
                c = __builtin_amdgcn_mfma_f32_16x16x32_bf16(afrag[rt][ks], bfrag[ks], c, 0, 0, 0);
            #pragma unroll
            for (int r = 0; r < 4; ++r)
                sums[rt][r] += __builtin_amdgcn_exp2f(fmaf(c[r], LOG2E, bg2));
        }
    }

    #pragma unroll
    for (int off = 1; off < 16; off <<= 1)
        #pragma unroll
        for (int rt = 0; rt < 4; ++rt)
            #pragma unroll
            for (int r = 0; r < 4; ++r)
                sums[rt][r] += __shfl_xor(sums[rt][r], off, 64);

    if (col16 == 0) {
        #pragma unroll
        for (int rt = 0; rt < 4; ++rt)
            #pragma unroll
            for (int r = 0; r < 4; ++r) {
                const int row = rowbase + rt * 16 + quad * 4 + r;
                part_s[row * NSTREAM + sid] = sums[rt][r];
            }
    }
}

// ---------------- Kernel C: per-row finalize + fused mean (atomic) ----------------
__global__ __launch_bounds__(64) void k_final_row(
    const float* __restrict__ z, const short* __restrict__ wb,
    const float* __restrict__ b_gen, const int* __restrict__ ctxw,
    const float* __restrict__ part_s, const float* __restrict__ kl,
    float* __restrict__ out)
{
    const int b = blockIdx.x;
    const int lane = threadIdx.x;    // 0..63

    // hoist all index-dependent loads (break the serial chain)
    int idxs[C];
    #pragma unroll
    for (int c = 0; c < C; ++c) idxs[c] = ctxw[b * C + c];
    unsigned uw[C];
    #pragma unroll
    for (int c = 0; c < C; ++c)
        uw[c] = ((const unsigned*)(wb + (size_t)idxs[c] * D))[lane];
    float sum_bg = 0.f;
    #pragma unroll
    for (int c = 0; c < C; ++c) sum_bg += b_gen[idxs[c]];

    float s = part_s[b * NSTREAM + lane]       + part_s[b * NSTREAM + 64 + lane]
            + part_s[b * NSTREAM + 128 + lane] + part_s[b * NSTREAM + 192 + lane];
    const float z0 = z[b * D + lane * 2];
    const float z1 = z[b * D + lane * 2 + 1];

    // per-lane dot accumulation over all contexts -> single reduction
    float acc = 0.f;
    #pragma unroll
    for (int c = 0; c < C; ++c) {
        const float w0 = __uint_as_float(uw[c] << 16);
        const float w1 = __uint_as_float(uw[c] & 0xFFFF0000u);
        acc = fmaf(z0, w0, acc);
        acc = fmaf(z1, w1, acc);
    }
    #pragma unroll
    for (int off = 32; off > 0; off >>= 1) {
        s   += __shfl_xor(s, off, 64);
        acc += __shfl_xor(acc, off, 64);
    }
    if (lane == 0) {
        const float lse = logf(s);
        const float recon = acc + sum_bg - C * lse;
        atomicAdd(out, (kl[b] - recon) * (1.f / B));
    }
}

extern "C" void kernel_launch(void* const* d_in, const int* in_sizes, int n_in,
                              void* d_out, int out_size, void* d_ws, size_t ws_size,
                              hipStream_t stream) {
    const int* x_batch = (const int*)d_in[0];
    const int* ctxw    = (const int*)d_in[1];
    const float* eps   = (const float*)d_in[2];
    const float* inf_emb = (const float*)d_in[3];
    const float* W_aff = (const float*)d_in[4];
    const float* b_aff = (const float*)d_in[5];
    const float* W_mu  = (const float*)d_in[6];
    const float* b_mu  = (const float*)d_in[7];
    const float* W_sig = (const float*)d_in[8];
    const float* b_sig = (const float*)d_in[9];
    const float* gen_sig = (const float*)d_in[10];
    const float* W_gen = (const float*)d_in[11];
    const float* b_gen = (const float*)d_in[12];
    float* out = (float*)d_out;

    char* ws = (char*)d_ws;
    float* z      = (float*)ws;   ws += (size_t)B * D * 4;
    float* part_s = (float*)ws;   ws += (size_t)B * NSTREAM * 4;
    float* kl     = (float*)ws;   ws += (size_t)B * 4;
    float* bg2    = (float*)ws;   ws += (size_t)NVPAD * 4;
    float* hpart  = (float*)ws;   ws += (size_t)2 * B * D * 4;
    short* z_bf   = (short*)ws;   ws += (size_t)B * D * 2;
    short* w_bf   = (short*)ws;   ws += (size_t)NVPAD * D * 2;
    short* waff_bf = (short*)ws;  ws += (size_t)128 * 256 * 2;
    short* wmu_bf  = (short*)ws;  ws += (size_t)128 * 128 * 2;
    short* wsig_bf = (short*)ws;  ws += (size_t)128 * 128 * 2;

    const int conv_items = NG4 + 16384 + NVPAD / 4;
    hipLaunchKernelGGL(k_convert, dim3((conv_items + 255) / 256), dim3(256), 0, stream,
                       W_gen, W_aff, W_mu, W_sig, b_gen,
                       w_bf, waff_bf, wmu_bf, wsig_bf, bg2, out);
    hipLaunchKernelGGL(k_infer1, dim3(B / 16, 2), dim3(256), 0, stream,
                       x_batch, ctxw, inf_emb, waff_bf, b_aff, hpart);
    hipLaunchKernelGGL(k_infer2, dim3(B / 16), dim3(256), 0, stream,
                       x_batch, eps, hpart, wmu_bf, b_mu, wsig_bf, b_sig,
                       gen_sig, z, z_bf, kl);
    hipLaunchKernelGGL(k_lse_mfma, dim3(B / 256 * NSTREAM), dim3(256), 0, stream,
                       z_bf, w_bf, bg2, part_s);
    hipLaunchKernelGGL(k_final_row, dim3(B), dim3(64), 0, stream,
                       z, w_bf, b_gen, ctxw, part_s, kl, out);
}

// Round 6
// 211.286 us; speedup vs baseline: 1.1449x; 1.1449x over previous
//
#include <hip/hip_runtime.h>
#include <float.h>
#include <math.h>

#define NV 50257
#define D 128
#define B 2048
#define C 10

#define NVPAD 50272                 // 3142 * 16
#define NTILES (NVPAD / 16)         // 3142 col-tiles of 16
#define NSTREAM 96                  // vocab streams; 96 = 12 streams/XCD, XCD = s%8 free
#define NG4 (NVPAD * D / 4)         // float4 count of padded W_gen
#define LOG2E 1.44269504088896f

typedef __attribute__((ext_vector_type(8))) short short8;
typedef __attribute__((ext_vector_type(4))) float float4v;

__device__ __forceinline__ float softplus_f(float x) {
    return fmaxf(x, 0.f) + log1pf(expf(-fabsf(x)));
}

__device__ __forceinline__ short f2bf(float f) {
    unsigned u = __float_as_uint(f);
    unsigned r = (u + 0x7FFFu + ((u >> 16) & 1u)) >> 16;   // RNE
    return (short)r;
}

// ---------------- Kernel W: bf16 converts + bg2 table + out zeroing ----------------
__global__ __launch_bounds__(256) void k_convert(
    const float* __restrict__ wg, const float* __restrict__ waff,
    const float* __restrict__ wmu, const float* __restrict__ wsig,
    const float* __restrict__ b_gen,
    short* __restrict__ wg_o, short* __restrict__ waff_o,
    short* __restrict__ wmu_o, short* __restrict__ wsig_o,
    float* __restrict__ bg2, float* __restrict__ out)
{
    const int i4 = blockIdx.x * 256 + threadIdx.x;      // float4 index
    if (i4 == 0) out[0] = 0.f;
    if (i4 < NG4) {
        const int e0 = i4 * 4;
        short4 o;
        if (e0 < NV * D) {
            const float4 g = ((const float4*)wg)[i4];
            o.x = f2bf(g.x); o.y = f2bf(g.y); o.z = f2bf(g.z); o.w = f2bf(g.w);
        } else {
            o.x = o.y = o.z = o.w = 0;
        }
        ((short4*)wg_o)[i4] = o;
        return;
    }
    const int j = i4 - NG4;
    if (j < 16384) {
        const float4* src; short4* dst; int jj;
        if (j < 8192)       { src = (const float4*)waff; dst = (short4*)waff_o; jj = j; }
        else if (j < 12288) { src = (const float4*)wmu;  dst = (short4*)wmu_o;  jj = j - 8192; }
        else                { src = (const float4*)wsig; dst = (short4*)wsig_o; jj = j - 12288; }
        const float4 g = src[jj];
        short4 o;
        o.x = f2bf(g.x); o.y = f2bf(g.y); o.z = f2bf(g.z); o.w = f2bf(g.w);
        dst[jj] = o;
    } else {
        const int jj = j - 16384;                       // bg2 float4 index
        if (jj < NVPAD / 4) {
            const int e0 = jj * 4;
            float4 o;
            o.x = (e0 + 0 < NV) ? b_gen[e0 + 0] * LOG2E : -INFINITY;
            o.y = (e0 + 1 < NV) ? b_gen[e0 + 1] * LOG2E : -INFINITY;
            o.z = (e0 + 2 < NV) ? b_gen[e0 + 2] * LOG2E : -INFINITY;
            o.w = (e0 + 3 < NV) ? b_gen[e0 + 3] * LOG2E : -INFINITY;
            ((float4*)bg2)[jj] = o;
        }
    }
}

// ---------------- Kernel A1: GEMM1 partial (context halves across blocks) ----------------
__global__ __launch_bounds__(256) void k_infer1(
    const int* __restrict__ x_batch, const int* __restrict__ ctxw,
    const float* __restrict__ inf_emb,
    const short* __restrict__ waff_bf, const float* __restrict__ b_aff,
    float* __restrict__ hpart)
{
    const int b0 = blockIdx.x * 16;
    const int h = blockIdx.y;
    const int t = threadIdx.x;
    const int wv = t >> 6;
    const int lane = t & 63;
    const int col16 = lane & 15;
    const int quad = lane >> 4;

    __shared__ float hsp[4][16][132];

    const int brow = b0 + col16;
    const int cidx = x_batch[brow];

    short8 ce[4];
    #pragma unroll
    for (int ks = 0; ks < 4; ++ks) {
        const float* p = inf_emb + (size_t)cidx * D + ks * 32 + quad * 8;
        const float4 g0 = *(const float4*)p;
        const float4 g1 = *(const float4*)(p + 4);
        short8 v;
        v[0] = f2bf(g0.x); v[1] = f2bf(g0.y); v[2] = f2bf(g0.z); v[3] = f2bf(g0.w);
        v[4] = f2bf(g1.x); v[5] = f2bf(g1.y); v[6] = f2bf(g1.z); v[7] = f2bf(g1.w);
        ce[ks] = v;
    }

    float4v U[8];
    #pragma unroll
    for (int dt = 0; dt < 8; ++dt) {
        float4v acc = {0.f, 0.f, 0.f, 0.f};
        #pragma unroll
        for (int ks = 0; ks < 4; ++ks) {
            const short8 bw = *(const short8*)(waff_bf + (dt * 16 + col16) * 256 + ks * 32 + quad * 8);
            acc = __builtin_amdgcn_mfma_f32_16x16x32_bf16(ce[ks], bw, acc, 0, 0, 0);
        }
        U[dt] = acc;
    }
    float ba[8];
    #pragma unroll
    for (int dt = 0; dt < 8; ++dt) ba[dt] = b_aff[dt * 16 + col16];

    float4v H[8];
    #pragma unroll
    for (int dt = 0; dt < 8; ++dt) H[dt] = (float4v){0.f, 0.f, 0.f, 0.f};

    for (int c = h * 5 + wv; c < h * 5 + 5; c += 4) {
        const int widx = ctxw[brow * C + c];
        short8 cx[4];
        #pragma unroll
        for (int ks = 0; ks < 4; ++ks) {
            const float* p = inf_emb + (size_t)widx * D + ks * 32 + quad * 8;
            const float4 g0 = *(const float4*)p;
            const float4 g1 = *(const float4*)(p + 4);
            short8 v;
            v[0] = f2bf(g0.x); v[1] = f2bf(g0.y); v[2] = f2bf(g0.z); v[3] = f2bf(g0.w);
            v[4] = f2bf(g1.x); v[5] = f2bf(g1.y); v[6] = f2bf(g1.z); v[7] = f2bf(g1.w);
            cx[ks] = v;
        }
        #pragma unroll
        for (int dt = 0; dt < 8; ++dt) {
            float4v a = {0.f, 0.f, 0.f, 0.f};
            #pragma unroll
            for (int ks = 0; ks < 4; ++ks) {
                const short8 bw = *(const short8*)(waff_bf + (dt * 16 + col16) * 256 + 128 + ks * 32 + quad * 8);
                a = __builtin_amdgcn_mfma_f32_16x16x32_bf16(cx[ks], bw, a, 0, 0, 0);
            }
            #pragma unroll
            for (int r = 0; r < 4; ++r)
                H[dt][r] += fmaxf(U[dt][r] + a[r] + ba[dt], 0.f);
        }
    }

    #pragma unroll
    for (int dt = 0; dt < 8; ++dt)
        #pragma unroll
        for (int r = 0; r < 4; ++r)
            hsp[wv][quad * 4 + r][dt * 16 + col16] = H[dt][r];
    __syncthreads();

    #pragma unroll
    for (int i = t; i < 16 * 128; i += 256) {
        const int row = i >> 7, d = i & 127;
        const float s = hsp[0][row][d] + hsp[1][row][d] + hsp[2][row][d] + hsp[3][row][d];
        hpart[((size_t)h * B + b0 + row) * D + d] = s;
    }
}

// ---------------- Kernel A2: combine halves, GEMM2 (mu/sig), epilogue ----------------
__global__ __launch_bounds__(256) void k_infer2(
    const int* __restrict__ x_batch, const float* __restrict__ eps,
    const float* __restrict__ hpart,
    const short* __restrict__ wmu_bf, const float* __restrict__ b_mu,
    const short* __restrict__ wsig_bf, const float* __restrict__ b_sig,
    const float* __restrict__ gen_sig_emb,
    float* __restrict__ z_out, short* __restrict__ zb_out,
    float* __restrict__ kl_out)
{
    const int b0 = blockIdx.x * 16;
    const int t = threadIdx.x;
    const int wv = t >> 6;
    const int lane = t & 63;
    const int col16 = lane & 15;
    const int quad = lane >> 4;

    __shared__ float kl_s[4][16];

    short8 ha[4];
    #pragma unroll
    for (int ks = 0; ks < 4; ++ks) {
        const int off = ks * 32 + quad * 8;
        const float* p0 = hpart + ((size_t)b0 + col16) * D + off;
        const float* p1 = p0 + (size_t)B * D;
        const float4 a0 = *(const float4*)p0;
        const float4 a1 = *(const float4*)(p0 + 4);
        const float4 b0v = *(const float4*)p1;
        const float4 b1v = *(const float4*)(p1 + 4);
        short8 v;
        v[0] = f2bf(a0.x + b0v.x); v[1] = f2bf(a0.y + b0v.y);
        v[2] = f2bf(a0.z + b0v.z); v[3] = f2bf(a0.w + b0v.w);
        v[4] = f2bf(a1.x + b1v.x); v[5] = f2bf(a1.y + b1v.y);
        v[6] = f2bf(a1.z + b1v.z); v[7] = f2bf(a1.w + b1v.w);
        ha[ks] = v;
    }

    int xb2[4];
    #pragma unroll
    for (int r = 0; r < 4; ++r) xb2[r] = x_batch[b0 + quad * 4 + r];

    float klp[4] = {0.f, 0.f, 0.f, 0.f};
    #pragma unroll
    for (int p = 0; p < 2; ++p) {
        const int nt = wv * 2 + p;
        float4v mu4 = {0.f, 0.f, 0.f, 0.f};
        float4v sg4 = {0.f, 0.f, 0.f, 0.f};
        #pragma unroll
        for (int ks = 0; ks < 4; ++ks) {
            const short8 bm = *(const short8*)(wmu_bf + (nt * 16 + col16) * 128 + ks * 32 + quad * 8);
            const short8 bs = *(const short8*)(wsig_bf + (nt * 16 + col16) * 128 + ks * 32 + quad * 8);
            mu4 = __builtin_amdgcn_mfma_f32_16x16x32_bf16(ha[ks], bm, mu4, 0, 0, 0);
            sg4 = __builtin_amdgcn_mfma_f32_16x16x32_bf16(ha[ks], bs, sg4, 0, 0, 0);
        }
        const int d = nt * 16 + col16;
        const float bmu = b_mu[d];
        const float bsg = b_sig[d];
        #pragma unroll
        for (int r = 0; r < 4; ++r) {
            const int b = b0 + quad * 4 + r;
            const float mu = mu4[r] + bmu;
            const float sg = sg4[r] + bsg;
            const float isig = softplus_f(sg);
            const float e = eps[b * D + d];
            const float zz = fmaf(e, isig, mu);
            z_out[b * D + d] = zz;
            zb_out[b * D + d] = f2bf(zz * LOG2E);    // pre-scaled: LSE kernel works in log2
            const float gs = softplus_f(gen_sig_emb[(size_t)xb2[r] * D + d]);
            const float diff = mu - gs;
            klp[r] += logf(gs / isig) + (isig * isig + diff * diff) / (2.f * gs * gs) - 0.5f;
        }
    }
    #pragma unroll
    for (int off = 1; off < 16; off <<= 1)
        #pragma unroll
        for (int r = 0; r < 4; ++r)
            klp[r] += __shfl_xor(klp[r], off, 64);
    if (col16 == 0) {
        #pragma unroll
        for (int r = 0; r < 4; ++r)
            kl_s[wv][quad * 4 + r] = klp[r];
    }
    __syncthreads();
    if (t < 16) kl_out[b0 + t] = kl_s[0][t] + kl_s[1][t] + kl_s[2][t] + kl_s[3][t];
}

// ---------------- Kernel B: MFMA sum-exp, register double-buffer prefetch ----------------
// grid 768 = 8 row-blocks x 96 streams (bid = x*96 + s). 96%8==0 -> XCD = s%8:
// per-XCD W set = 12 streams (~1.6 MB). 3 blocks/CU exactly at ~164 VGPR occupancy.
// Each wave: 64 rows x stream of 16-col tiles, 2 tiles/iter + next-pair prefetch.
#define LOADP(bf, g, T) { \
    const int tt_ = ((T) < NTILES) ? (T) : 0; \
    const short* wp_ = wb + (size_t)(tt_ * 16 + col16) * D + quad * 8; \
    bf[0] = *(const short8*)(wp_); \
    bf[1] = *(const short8*)(wp_ + 32); \
    bf[2] = *(const short8*)(wp_ + 64); \
    bf[3] = *(const short8*)(wp_ + 96); \
    g = ((T) < NTILES) ? bg2t[tt_ * 16 + col16] : -INFINITY; }

#define COMP(bf, g) { \
    _Pragma("unroll") \
    for (int rt = 0; rt < 4; ++rt) { \
        float4v c = {0.f, 0.f, 0.f, 0.f}; \
        _Pragma("unroll") \
        for (int ks = 0; ks < 4; ++ks) \
            c = __builtin_amdgcn_mfma_f32_16x16x32_bf16(afrag[rt][ks], bf[ks], c, 0, 0, 0); \
        _Pragma("unroll") \
        for (int r = 0; r < 4; ++r) \
            sums[rt][r] += __builtin_amdgcn_exp2f(c[r] + g); \
    } }

__global__ __launch_bounds__(256) void k_lse_mfma(
    const short* __restrict__ zb, const short* __restrict__ wb,
    const float* __restrict__ bg2t, float* __restrict__ part_s)
{
    const int bid = blockIdx.x;
    const int s = bid % 96;                         // stream; XCD = s%8
    const int x = bid / 96;                         // row block (256 rows)
    const int t = threadIdx.x;
    const int wv = t >> 6;
    const int lane = t & 63;
    const int col16 = lane & 15;
    const int quad = lane >> 4;
    const int rowbase = x * 256 + wv * 64;

    short8 afrag[4][4];
    #pragma unroll
    for (int rt = 0; rt < 4; ++rt)
        #pragma unroll
        for (int ks = 0; ks < 4; ++ks)
            afrag[rt][ks] = *(const short8*)(zb + (rowbase + rt * 16 + col16) * D
                                                + ks * 32 + quad * 8);

    float sums[4][4];
    #pragma unroll
    for (int rt = 0; rt < 4; ++rt)
        #pragma unroll
        for (int r = 0; r < 4; ++r) sums[rt][r] = 0.f;

    // 17 pairs cover ceil(3142/96)=33 tiles; out-of-range tiles clamp addr, bg=-inf.
    short8 bA[4], bB[4], bC[4], bD[4];
    float gA, gB, gC, gD;
    LOADP(bA, gA, s);
    LOADP(bB, gB, s + 96);
    #pragma unroll 1
    for (int p = 0; p < 16; p += 2) {
        int base = s + (p + 1) * 192;
        LOADP(bC, gC, base); LOADP(bD, gD, base + 96);
        COMP(bA, gA); COMP(bB, gB);
        base = s + (p + 2) * 192;
        LOADP(bA, gA, base); LOADP(bB, gB, base + 96);
        COMP(bC, gC); COMP(bD, gD);
    }
    COMP(bA, gA); COMP(bB, gB);                     // pair 16

    #pragma unroll
    for (int off = 1; off < 16; off <<= 1)
        #pragma unroll
        for (int rt = 0; rt < 4; ++rt)
            #pragma unroll
            for (int r = 0; r < 4; ++r)
                sums[rt][r] += __shfl_xor(sums[rt][r], off, 64);

    if (col16 == 0) {
        #pragma unroll
        for (int rt = 0; rt < 4; ++rt)
            #pragma unroll
            for (int r = 0; r < 4; ++r) {
                const int row = rowbase + rt * 16 + quad * 4 + r;
                part_s[row * NSTREAM + s] = sums[rt][r];
            }
    }
}

// ---------------- Kernel C: finalize, 8 rows/block, one atomic per block ----------------
__global__ __launch_bounds__(256) void k_final(
    const float* __restrict__ z, const short* __restrict__ wb,
    const float* __restrict__ b_gen, const int* __restrict__ ctxw,
    const float* __restrict__ part_s, const float* __restrict__ kl,
    float* __restrict__ out)
{
    const int t = threadIdx.x;
    const int wv = t >> 6;
    const int lane = t & 63;
    __shared__ float red[4];

    float wsum = 0.f;
    #pragma unroll
    for (int rr = 0; rr < 2; ++rr) {
        const int b = blockIdx.x * 8 + wv * 2 + rr;

        int idxs[C];
        #pragma unroll
        for (int c = 0; c < C; ++c) idxs[c] = ctxw[b * C + c];
        unsigned uw[C];
        #pragma unroll
        for (int c = 0; c < C; ++c)
            uw[c] = ((const unsigned*)(wb + (size_t)idxs[c] * D))[lane];
        float sum_bg = 0.f;
        #pragma unroll
        for (int c = 0; c < C; ++c) sum_bg += b_gen[idxs[c]];

        float sv = part_s[b * NSTREAM + lane];
        if (lane < 32) sv += part_s[b * NSTREAM + 64 + lane];
        const float z0 = z[b * D + lane * 2];
        const float z1 = z[b * D + lane * 2 + 1];

        float acc = 0.f;
        #pragma unroll
        for (int c = 0; c < C; ++c) {
            const float w0 = __uint_as_float(uw[c] << 16);
            const float w1 = __uint_as_float(uw[c] & 0xFFFF0000u);
            acc = fmaf(z0, w0, acc);
            acc = fmaf(z1, w1, acc);
        }
        #pragma unroll
        for (int off = 32; off > 0; off >>= 1) {
            sv  += __shfl_xor(sv, off, 64);
            acc += __shfl_xor(acc, off, 64);
        }
        if (lane == 0) {
            const float lse = logf(sv);
            const float recon = acc + sum_bg - C * lse;
            wsum += kl[b] - recon;
        }
    }
    if (lane == 0) red[wv] = wsum;
    __syncthreads();
    if (t == 0) atomicAdd(out, (red[0] + red[1] + red[2] + red[3]) * (1.f / B));
}

extern "C" void kernel_launch(void* const* d_in, const int* in_sizes, int n_in,
                              void* d_out, int out_size, void* d_ws, size_t ws_size,
                              hipStream_t stream) {
    const int* x_batch = (const int*)d_in[0];
    const int* ctxw    = (const int*)d_in[1];
    const float* eps   = (const float*)d_in[2];
    const float* inf_emb = (const float*)d_in[3];
    const float* W_aff = (const float*)d_in[4];
    const float* b_aff = (const float*)d_in[5];
    const float* W_mu  = (const float*)d_in[6];
    const float* b_mu  = (const float*)d_in[7];
    const float* W_sig = (const float*)d_in[8];
    const float* b_sig = (const float*)d_in[9];
    const float* gen_sig = (const float*)d_in[10];
    const float* W_gen = (const float*)d_in[11];
    const float* b_gen = (const float*)d_in[12];
    float* out = (float*)d_out;

    char* ws = (char*)d_ws;
    float* z      = (float*)ws;   ws += (size_t)B * D * 4;
    float* part_s = (float*)ws;   ws += (size_t)B * NSTREAM * 4;
    float* kl     = (float*)ws;   ws += (size_t)B * 4;
    float* bg2    = (float*)ws;   ws += (size_t)NVPAD * 4;
    float* hpart  = (float*)ws;   ws += (size_t)2 * B * D * 4;
    short* z_bf   = (short*)ws;   ws += (size_t)B * D * 2;
    short* w_bf   = (short*)ws;   ws += (size_t)NVPAD * D * 2;
    short* waff_bf = (short*)ws;  ws += (size_t)128 * 256 * 2;
    short* wmu_bf  = (short*)ws;  ws += (size_t)128 * 128 * 2;
    short* wsig_bf = (short*)ws;  ws += (size_t)128 * 128 * 2;

    const int conv_items = NG4 + 16384 + NVPAD / 4;
    hipLaunchKernelGGL(k_convert, dim3((conv_items + 255) / 256), dim3(256), 0, stream,
                       W_gen, W_aff, W_mu, W_sig, b_gen,
                       w_bf, waff_bf, wmu_bf, wsig_bf, bg2, out);
    hipLaunchKernelGGL(k_infer1, dim3(B / 16, 2), dim3(256), 0, stream,
                       x_batch, ctxw, inf_emb, waff_bf, b_aff, hpart);
    hipLaunchKernelGGL(k_infer2, dim3(B / 16), dim3(256), 0, stream,
                       x_batch, eps, hpart, wmu_bf, b_mu, wsig_bf, b_sig,
                       gen_sig, z, z_bf, kl);
    hipLaunchKernelGGL(k_lse_mfma, dim3(8 * NSTREAM), dim3(256), 0, stream,
                       z_bf, w_bf, bg2, part_s);
    hipLaunchKernelGGL(k_final, dim3(B / 8), dim3(256), 0, stream,
                       z, w_bf, b_gen, ctxw, part_s, kl, out);
}